// Round 8
// baseline (257.262 us; speedup 1.0000x reference)
//
#include <hip/hip_runtime.h>

typedef __attribute__((ext_vector_type(4))) int i32x4;

// ---------------------------------------------------------------------------
// Helpers
// ---------------------------------------------------------------------------
__device__ __forceinline__ void gload_lds16(const void* g, void* l) {
  // async global->LDS, 16B/lane. LDS dest must be wave-uniform base + lane*16.
  __builtin_amdgcn_global_load_lds((const __attribute__((address_space(1))) void*)g,
                                   (__attribute__((address_space(3))) void*)l,
                                   16, 0, 0);
}

#define BARRIER() __builtin_amdgcn_s_barrier()
#define VMCNT0()  asm volatile("s_waitcnt vmcnt(0)" ::: "memory")

// ---------------------------------------------------------------------------
// Fused quantize f32 -> int8 for both x and w (round-half-even, clamp +-127)
// ---------------------------------------------------------------------------
__global__ void quant_both_kernel(const float* __restrict__ x,
                                  const float* __restrict__ w,
                                  signed char* __restrict__ qx,
                                  signed char* __restrict__ qw,
                                  const float* __restrict__ amax_x,
                                  const float* __restrict__ amax_w,
                                  int nx4, int nw4) {
  const float sx = 127.0f / amax_x[0];
  const float sw = 127.0f / amax_w[0];
  int i = blockIdx.x * blockDim.x + threadIdx.x;
  const int stride = gridDim.x * blockDim.x;
  const int ntot = nx4 + nw4;
  for (; i < ntot; i += stride) {
    const bool isx = i < nx4;
    const float4* src = isx ? (const float4*)x : (const float4*)w;
    int* dst = isx ? (int*)qx : (int*)qw;
    const int j = isx ? i : i - nx4;
    const float s = isx ? sx : sw;
    float4 v = src[j];
    int q0 = (int)rintf(fminf(fmaxf(v.x * s, -127.0f), 127.0f));
    int q1 = (int)rintf(fminf(fmaxf(v.y * s, -127.0f), 127.0f));
    int q2 = (int)rintf(fminf(fmaxf(v.z * s, -127.0f), 127.0f));
    int q3 = (int)rintf(fminf(fmaxf(v.w * s, -127.0f), 127.0f));
    dst[j] = (q0 & 255) | ((q1 & 255) << 8) | ((q2 & 255) << 16) | ((q3 & 255) << 24);
  }
}

// ---------------------------------------------------------------------------
// 256x256 int8 GEMM, B-operand DIRECT global->register (no LDS for B).
// out[N,M] = dequant(qx[N,K] . qw[M,K]^T) + bias
// 512 thr = 8 waves (2M x 4N), per-wave 128x64, mfma_i32_16x16x64_i8, BK=128.
// Only A staged in LDS (2 x 32 KiB dbuf, chunk^=(row&7) swizzle, 0-conflict).
// B frags are wave-private: loaded global->VGPR one K-tile ahead (2x32 regs).
// => ONE barrier + ONE vmcnt(0) gate per K-tile (64 MFMA between barriers);
//    gate sits ~1 full K-tile after issue, so it drains nothing hot.
// ---------------------------------------------------------------------------
__global__ __launch_bounds__(512, 2) void gemm_i8_bdir(
    const signed char* __restrict__ qx,   // [N,K]
    const signed char* __restrict__ qw,   // [M,K]
    const float* __restrict__ bias,       // [M]
    const float* __restrict__ amax_x,
    const float* __restrict__ amax_w,
    float* __restrict__ out,              // [N,M]
    int N, int M, int K) {
  constexpr int BKB = 128;  // K bytes per tile

  __shared__ signed char Ald[2][256 * 128];  // A dbuf, 32 KiB each

  const int tid  = threadIdx.x;
  const int lane = tid & 63;
  const int wid  = tid >> 6;
  const int wm   = wid >> 2;   // 0..1
  const int wn   = wid & 3;    // 0..3
  const int l15  = lane & 15;
  const int l4   = lane >> 4;

  // bijective XCD-aware block swizzle (nwg = 512, divisible by 8)
  const int nbn = M >> 8;                      // 16
  const int nwg = (N >> 8) * nbn;              // 512
  const int cpx = nwg >> 3;
  const int swz = (blockIdx.x & 7) * cpx + (blockIdx.x >> 3);
  const int rowBase = (swz / nbn) << 8;
  const int colBase = (swz % nbn) << 8;

  // A staging sources (thread t covers slots {h*1024 + L*512 + t};
  // logical row = slot>>3, chunk = (slot&7)^(row&7); LDS dest linear).
  const signed char* sA[2][2];
#pragma unroll
  for (int h = 0; h < 2; ++h)
#pragma unroll
    for (int L = 0; L < 2; ++L) {
      const int slot = h * 1024 + L * 512 + tid;
      const int row  = slot >> 3;
      const int c    = (slot & 7) ^ (row & 7);
      sA[h][L] = qx + (size_t)(rowBase + row) * K + c * 16;
    }

  // B direct-load bases: one per nj; ks picked via 64B imm offset.
  const signed char* sB[4];
#pragma unroll
  for (int nj = 0; nj < 4; ++nj)
    sB[nj] = qw + (size_t)(colBase + wn * 64 + nj * 16 + l15) * K + l4 * 16;

#define STAGEA(p, kt)                                                    \
  do {                                                                   \
    gload_lds16(sA[0][0] + (kt) * BKB, Ald[p] + tid * 16);               \
    gload_lds16(sA[0][1] + (kt) * BKB, Ald[p] + 8192 + tid * 16);        \
    gload_lds16(sA[1][0] + (kt) * BKB, Ald[p] + 16384 + tid * 16);       \
    gload_lds16(sA[1][1] + (kt) * BKB, Ald[p] + 24576 + tid * 16);       \
  } while (0)

  // A fragment addressing: row = wm*128 + mi*16 + l15 (row&7 == l15&7).
  const int ck0 = ((l4) ^ (l15 & 7)) * 16;       // ks=0 chunk
  const int ck1 = ((4 + l4) ^ (l15 & 7)) * 16;   // ks=1 chunk
  const int aBase = (wm * 128 + l15) * 128;

  i32x4 acc[8][4] = {{{0}}};
  i32x4 bregE[4][2], bregO[4][2];  // B double-buffer (even/odd K-tile)

#define LOADB(DST, kt)                                                   \
  {                                                                      \
    _Pragma("unroll") for (int nj = 0; nj < 4; ++nj) {                   \
      DST[nj][0] = *(const i32x4*)(sB[nj] + (kt) * BKB);                 \
      DST[nj][1] = *(const i32x4*)(sB[nj] + (kt) * BKB + 64);            \
    }                                                                    \
  }

  // quarter-phase: M-half mh, k-sub ks; 4 ds_read + 16 MFMA.
#define QPHASE(p, mh, ks, BREG)                                          \
  {                                                                      \
    i32x4 af[4];                                                         \
    _Pragma("unroll") for (int q = 0; q < 4; ++q)                        \
        af[q] = *(const i32x4*)(Ald[p] + aBase + (mh) * 8192 + q * 2048  \
                                + ((ks) ? ck1 : ck0));                   \
    __builtin_amdgcn_s_setprio(1);                                       \
    _Pragma("unroll") for (int q = 0; q < 4; ++q)                        \
        _Pragma("unroll") for (int nj = 0; nj < 4; ++nj)                 \
            acc[(mh) * 4 + q][nj] = __builtin_amdgcn_mfma_i32_16x16x64_i8( \
                af[q], BREG[nj][ks], acc[(mh) * 4 + q][nj], 0, 0, 0);    \
    __builtin_amdgcn_s_setprio(0);                                       \
  }

  // one K-tile: issue next-tile B + A-stage, compute current, gate.
#define KTILE(p, BCUR, BNXT, ktNext)                                     \
  {                                                                      \
    LOADB(BNXT, ktNext);                                                 \
    STAGEA(p ^ 1, ktNext);                                               \
    QPHASE(p, 0, 0, BCUR);                                               \
    QPHASE(p, 0, 1, BCUR);                                               \
    QPHASE(p, 1, 0, BCUR);                                               \
    QPHASE(p, 1, 1, BCUR);                                               \
    VMCNT0(); /* drains ktNext's loads, issued ~1 K-tile ago */          \
    BARRIER();                                                           \
  }

  const int T = K / BKB;  // 32 K-tiles

  // prologue: tile0 -> Ald[0] + bregE; drain; publish.
  LOADB(bregE, 0);
  STAGEA(0, 0);
  VMCNT0();
  BARRIER();

  for (int it = 0; it < T / 2; ++it) {
    const int t1 = 2 * it + 1;                             // always valid
    const int t2 = (2 * it + 2 < T) ? 2 * it + 2 : T - 1;  // clamped, never consumed
    KTILE(0, bregE, bregO, t1);
    KTILE(1, bregO, bregE, t2);
  }

  // epilogue: dequant + bias. C/D: col = lane&15, row = (lane>>4)*4 + reg
  const float dq = amax_x[0] * amax_w[0] * (1.0f / (127.0f * 127.0f));
#pragma unroll
  for (int nj = 0; nj < 4; ++nj) {
    const int col = colBase + wn * 64 + nj * 16 + l15;
    const float bv = bias[col];
#pragma unroll
    for (int mi = 0; mi < 8; ++mi) {
      const int row = rowBase + wm * 128 + mi * 16 + l4 * 4;
#pragma unroll
      for (int r = 0; r < 4; ++r)
        out[(size_t)(row + r) * M + col] = (float)acc[mi][nj][r] * dq + bv;
    }
  }
#undef STAGEA
#undef LOADB
#undef QPHASE
#undef KTILE
}

// ---------------------------------------------------------------------------
// Launch
// ---------------------------------------------------------------------------
extern "C" void kernel_launch(void* const* d_in, const int* in_sizes, int n_in,
                              void* d_out, int out_size, void* d_ws, size_t ws_size,
                              hipStream_t stream) {
  const float* x      = (const float*)d_in[0];
  const float* w      = (const float*)d_in[1];
  const float* bias   = (const float*)d_in[2];
  const float* amax_x = (const float*)d_in[3];
  const float* amax_w = (const float*)d_in[4];
  float* out = (float*)d_out;

  const int M = in_sizes[2];                    // 4096
  const int K = in_sizes[1] / M;                // 4096
  const int N = (int)((long)in_sizes[0] / K);   // 8192

  signed char* qx = (signed char*)d_ws;         // [N,K] int8
  signed char* qw = qx + (size_t)N * K;         // [M,K] int8

  const int nx4 = N * (K / 4);
  const int nw4 = M * (K / 4);
  quant_both_kernel<<<2048, 256, 0, stream>>>(x, w, qx, qw, amax_x, amax_w,
                                              nx4, nw4);

  const int nwg = (N / 256) * (M / 256);        // 512
  gemm_i8_bdir<<<nwg, 512, 0, stream>>>(qx, qw, bias, amax_x, amax_w, out,
                                        N, M, K);
}

// Round 9
// 231.491 us; speedup vs baseline: 1.1113x; 1.1113x over previous
//
#include <hip/hip_runtime.h>

typedef __attribute__((ext_vector_type(4))) int i32x4;

// ---------------------------------------------------------------------------
// Helpers
// ---------------------------------------------------------------------------
__device__ __forceinline__ void gload_lds16(const void* g, void* l) {
  // async global->LDS, 16B/lane. LDS dest must be wave-uniform base + lane*16.
  __builtin_amdgcn_global_load_lds((const __attribute__((address_space(1))) void*)g,
                                   (__attribute__((address_space(3))) void*)l,
                                   16, 0, 0);
}

#define BARRIER()  __builtin_amdgcn_s_barrier()
#define LGKM0()    asm volatile("s_waitcnt lgkmcnt(0)" ::: "memory")
#define VMCNT0()   asm volatile("s_waitcnt vmcnt(0)" ::: "memory")
#define VMCNT16()  asm volatile("s_waitcnt vmcnt(16)" ::: "memory")

// ---------------------------------------------------------------------------
// Fused quantize f32 -> int8 for both x and w (round-half-even, clamp +-127)
// ---------------------------------------------------------------------------
__global__ void quant_both_kernel(const float* __restrict__ x,
                                  const float* __restrict__ w,
                                  signed char* __restrict__ qx,
                                  signed char* __restrict__ qw,
                                  const float* __restrict__ amax_x,
                                  const float* __restrict__ amax_w,
                                  int nx4, int nw4) {
  const float sx = 127.0f / amax_x[0];
  const float sw = 127.0f / amax_w[0];
  int i = blockIdx.x * blockDim.x + threadIdx.x;
  const int stride = gridDim.x * blockDim.x;
  const int ntot = nx4 + nw4;
  for (; i < ntot; i += stride) {
    const bool isx = i < nx4;
    const float4* src = isx ? (const float4*)x : (const float4*)w;
    int* dst = isx ? (int*)qx : (int*)qw;
    const int j = isx ? i : i - nx4;
    const float s = isx ? sx : sw;
    float4 v = src[j];
    int q0 = (int)rintf(fminf(fmaxf(v.x * s, -127.0f), 127.0f));
    int q1 = (int)rintf(fminf(fmaxf(v.y * s, -127.0f), 127.0f));
    int q2 = (int)rintf(fminf(fmaxf(v.z * s, -127.0f), 127.0f));
    int q3 = (int)rintf(fminf(fmaxf(v.w * s, -127.0f), 127.0f));
    dst[j] = (q0 & 255) | ((q1 & 255) << 8) | ((q2 & 255) << 16) | ((q3 & 255) << 24);
  }
}

// ---------------------------------------------------------------------------
// "Fat-wave" 256x256 int8 GEMM: 4 waves (2M x 2N), per-wave 128x128,
// mfma_i32_16x16x64_i8, BK=128, 1 wave/SIMD, 1 block/CU.
// out[N,M] = dequant(qx[N,K] . qw[M,K]^T) + bias
// Rationale: each LDS b128 read feeds 8 MFMAs (2x prior), LDS traffic/iter
// 3x lower, and only ONE barrier + ONE vmcnt gate per K-tile (128 MFMA
// between barriers) -> compiler freely interleaves reads under MFMAs.
// acc 256 regs (->AGPRs) + 128 operand regs, ~410 total at 1 wave/EU.
// LDS: A[2][32K] + B[2][32K] = 128 KiB. Swizzle chunk^=(row&7) (0-conflict,
// verified), inverse on global source (rule #21), forward on ds_read.
// Gate: LGKM0 (own reads drained) -> VMCNT0 (t+1 loads, issued a full tile
// ago, never hot) -> BARRIER (publish) -> STAGE t+2 into just-freed buffer.
// ---------------------------------------------------------------------------
__global__ __launch_bounds__(256, 1) void gemm_i8_fat(
    const signed char* __restrict__ qx,   // [N,K]
    const signed char* __restrict__ qw,   // [M,K]
    const float* __restrict__ bias,       // [M]
    const float* __restrict__ amax_x,
    const float* __restrict__ amax_w,
    float* __restrict__ out,              // [N,M]
    int N, int M, int K) {
  constexpr int BKB = 128;  // K bytes per tile

  __shared__ signed char Ald[2][32768];
  __shared__ signed char Bld[2][32768];

  const int tid  = threadIdx.x;   // 0..255
  const int lane = tid & 63;
  const int wid  = tid >> 6;      // 0..3
  const int wm   = wid >> 1;      // 0..1 (128-row stripes)
  const int wn   = wid & 1;       // 0..1 (128-col stripes)
  const int l15  = lane & 15;
  const int l4   = lane >> 4;

  // bijective XCD-aware block swizzle (nwg = 512, divisible by 8)
  const int nbn = M >> 8;                      // 16
  const int nwg = (N >> 8) * nbn;              // 512
  const int cpx = nwg >> 3;
  const int swz = (blockIdx.x & 7) * cpx + (blockIdx.x >> 3);
  const int rowBase = (swz / nbn) << 8;
  const int colBase = (swz % nbn) << 8;

  // staging: tile = 256 rows x 8 chunks = 2048 slots; thread t covers
  // slots {L*256 + t}, L=0..7. row = L*32 + (t>>3); since L*32 % 8 == 0,
  // the swizzled chunk c = (t&7) ^ ((t>>3)&7) is L-independent.
  // LDS dest linear at slot*16 = L*4096 + t*16.
  const int srow = tid >> 3;
  const int sc   = (tid & 7) ^ (srow & 7);
  const signed char* qxs = qx + (size_t)(rowBase + srow) * K + sc * 16;
  const signed char* qws = qw + (size_t)(colBase + srow) * K + sc * 16;
  const size_t rstep = (size_t)32 * K;  // 32 rows per L unit

#define STAGE(p, kt)                                                        \
  {                                                                         \
    _Pragma("unroll") for (int L = 0; L < 8; ++L) {                         \
      gload_lds16(qxs + L * rstep + (kt) * BKB, Ald[p] + L * 4096 + tid * 16); \
      gload_lds16(qws + L * rstep + (kt) * BKB, Bld[p] + L * 4096 + tid * 16); \
    }                                                                       \
  }

  // fragment-read addressing (rows are mult of 16 + l15 -> row&7 == l15&7)
  const int ck0 = ((l4) ^ (l15 & 7)) * 16;       // ks=0 chunk
  const int ck1 = ((4 + l4) ^ (l15 & 7)) * 16;   // ks=1 chunk
  const int aBase = (wm * 128 + l15) * 128;
  const int bBase = (wn * 128 + l15) * 128;

  i32x4 acc[8][8] = {{{0}}};

  // one K-tile: 32 ds_read_b128 + 128 MFMA, then gate + stage t+2.
#define KTILE(p, ktNext)                                                    \
  {                                                                         \
    i32x4 af[8][2], bf[8][2];                                               \
    _Pragma("unroll") for (int mi = 0; mi < 8; ++mi) {                      \
      af[mi][0] = *(const i32x4*)(Ald[p] + aBase + mi * 2048 + ck0);        \
      af[mi][1] = *(const i32x4*)(Ald[p] + aBase + mi * 2048 + ck1);        \
    }                                                                       \
    _Pragma("unroll") for (int nj = 0; nj < 8; ++nj) {                      \
      bf[nj][0] = *(const i32x4*)(Bld[p] + bBase + nj * 2048 + ck0);        \
      bf[nj][1] = *(const i32x4*)(Bld[p] + bBase + nj * 2048 + ck1);        \
    }                                                                       \
    _Pragma("unroll") for (int mi = 0; mi < 8; ++mi)                        \
        _Pragma("unroll") for (int nj = 0; nj < 8; ++nj)                    \
            _Pragma("unroll") for (int ks = 0; ks < 2; ++ks)                \
                acc[mi][nj] = __builtin_amdgcn_mfma_i32_16x16x64_i8(        \
                    af[mi][ks], bf[nj][ks], acc[mi][nj], 0, 0, 0);          \
    LGKM0();   /* own reads of buf[p] fully drained */                      \
    VMCNT0();  /* t+1's loads (issued ~1 full tile ago) complete */         \
    BARRIER(); /* publish t+1; all waves done reading buf[p] */             \
    STAGE(p, ktNext); /* t+2 into the just-freed buffer */                  \
  }

  const int T = K / BKB;  // 32 K-tiles

  // prologue: stage t0 -> buf0 (16 loads), t1 -> buf1 (16 loads);
  // drain t0 (leave t1's 16 in flight); publish.
  STAGE(0, 0);
  STAGE(1, 1);
  VMCNT16();
  BARRIER();

  for (int it = 0; it < T / 2; ++it) {
    const int k2 = (2 * it + 2 < T) ? 2 * it + 2 : T - 1;  // clamped, never read
    const int k3 = (2 * it + 3 < T) ? 2 * it + 3 : T - 1;
    KTILE(0, k2);
    KTILE(1, k3);
  }

  VMCNT0();  // don't end the kernel with stray LDS-writing loads in flight

  // epilogue: dequant + bias. C/D: col = lane&15, row = (lane>>4)*4 + reg
  const float dq = amax_x[0] * amax_w[0] * (1.0f / (127.0f * 127.0f));
#pragma unroll
  for (int nj = 0; nj < 8; ++nj) {
    const int col = colBase + wn * 128 + nj * 16 + l15;
    const float bv = bias[col];
#pragma unroll
    for (int mi = 0; mi < 8; ++mi) {
      const int row = rowBase + wm * 128 + mi * 16 + l4 * 4;
#pragma unroll
      for (int r = 0; r < 4; ++r)
        out[(size_t)(row + r) * M + col] = (float)acc[mi][nj][r] * dq + bv;
    }
  }
#undef STAGE
#undef KTILE
}

// ---------------------------------------------------------------------------
// Launch
// ---------------------------------------------------------------------------
extern "C" void kernel_launch(void* const* d_in, const int* in_sizes, int n_in,
                              void* d_out, int out_size, void* d_ws, size_t ws_size,
                              hipStream_t stream) {
  const float* x      = (const float*)d_in[0];
  const float* w      = (const float*)d_in[1];
  const float* bias   = (const float*)d_in[2];
  const float* amax_x = (const float*)d_in[3];
  const float* amax_w = (const float*)d_in[4];
  float* out = (float*)d_out;

  const int M = in_sizes[2];                    // 4096
  const int K = in_sizes[1] / M;                // 4096
  const int N = (int)((long)in_sizes[0] / K);   // 8192

  signed char* qx = (signed char*)d_ws;         // [N,K] int8
  signed char* qw = qx + (size_t)N * K;         // [M,K] int8

  const int nx4 = N * (K / 4);
  const int nw4 = M * (K / 4);
  quant_both_kernel<<<2048, 256, 0, stream>>>(x, w, qx, qw, amax_x, amax_w,
                                              nx4, nw4);

  const int nwg = (N / 256) * (M / 256);        // 512
  gemm_i8_fat<<<nwg, 256, 0, stream>>>(qx, qw, bias, amax_x, amax_w, out,
                                       N, M, K);
}

// Round 10
// 190.194 us; speedup vs baseline: 1.3526x; 1.2171x over previous
//
#include <hip/hip_runtime.h>

typedef __attribute__((ext_vector_type(4))) int i32x4;

// ---------------------------------------------------------------------------
// Helpers
// ---------------------------------------------------------------------------
__device__ __forceinline__ void gload_lds16(const void* g, void* l) {
  // async global->LDS, 16B/lane. LDS dest must be wave-uniform base + lane*16.
  __builtin_amdgcn_global_load_lds((const __attribute__((address_space(1))) void*)g,
                                   (__attribute__((address_space(3))) void*)l,
                                   16, 0, 0);
}

#define BARRIER() __builtin_amdgcn_s_barrier()
#define LGKM0()   asm volatile("s_waitcnt lgkmcnt(0)" ::: "memory")
#define VMCNT4()  asm volatile("s_waitcnt vmcnt(4)" ::: "memory")

// ---------------------------------------------------------------------------
// Fused quantize f32 -> int8 for both x and w (round-half-even, clamp +-127)
// ---------------------------------------------------------------------------
__global__ void quant_both_kernel(const float* __restrict__ x,
                                  const float* __restrict__ w,
                                  signed char* __restrict__ qx,
                                  signed char* __restrict__ qw,
                                  const float* __restrict__ amax_x,
                                  const float* __restrict__ amax_w,
                                  int nx4, int nw4) {
  const float sx = 127.0f / amax_x[0];
  const float sw = 127.0f / amax_w[0];
  int i = blockIdx.x * blockDim.x + threadIdx.x;
  const int stride = gridDim.x * blockDim.x;
  const int ntot = nx4 + nw4;
  for (; i < ntot; i += stride) {
    const bool isx = i < nx4;
    const float4* src = isx ? (const float4*)x : (const float4*)w;
    int* dst = isx ? (int*)qx : (int*)qw;
    const int j = isx ? i : i - nx4;
    const float s = isx ? sx : sw;
    float4 v = src[j];
    int q0 = (int)rintf(fminf(fmaxf(v.x * s, -127.0f), 127.0f));
    int q1 = (int)rintf(fminf(fmaxf(v.y * s, -127.0f), 127.0f));
    int q2 = (int)rintf(fminf(fmaxf(v.z * s, -127.0f), 127.0f));
    int q3 = (int)rintf(fminf(fmaxf(v.w * s, -127.0f), 127.0f));
    dst[j] = (q0 & 255) | ((q1 & 255) << 8) | ((q2 & 255) << 16) | ((q3 & 255) << 24);
  }
}

// ---------------------------------------------------------------------------
// 256x256 8-phase int8 GEMM (verified round-3 kernel, verbatim).
// out[N,M] = dequant(qx[N,K] . qw[M,K]^T) + bias
// 512 thr = 8 waves (2M x 4N), per-wave 128x64, mfma_i32_16x16x64_i8,
// BK=128 int8 (2 k-subtiles of 64), LDS 2dbuf x (A,B) x [256][128B] = 128 KiB.
// Swizzle: 16B-chunk' = chunk ^ (row&7); applied to global SOURCE on staging
// (LDS dest linear, rule #21) and to the ds_read address. Measured 0 conflict.
// Gates: vmcnt(4) BEFORE the trailing barriers of P4/P8 (all waves drain,
// then barrier publishes) — counted, never 0 in the main loop.
// ---------------------------------------------------------------------------
__global__ __launch_bounds__(512, 2) void gemm_i8_8p(
    const signed char* __restrict__ qx,   // [N,K]
    const signed char* __restrict__ qw,   // [M,K]
    const float* __restrict__ bias,       // [M]
    const float* __restrict__ amax_x,
    const float* __restrict__ amax_w,
    float* __restrict__ out,              // [N,M]
    int N, int M, int K) {
  constexpr int BKB = 128;  // K bytes per tile

  __shared__ signed char lds[4][256 * 128];  // [A0,B0,A1,B1], 32 KiB each

  const int tid  = threadIdx.x;
  const int lane = tid & 63;
  const int wid  = tid >> 6;
  const int wm   = wid >> 2;   // 0..1
  const int wn   = wid & 3;    // 0..3
  const int l15  = lane & 15;
  const int l4   = lane >> 4;

  // bijective XCD-aware block swizzle (nwg = 512, divisible by 8)
  const int nbn = M >> 8;                      // 16
  const int nwg = (N >> 8) * nbn;              // 512
  const int cpx = nwg >> 3;
  const int swz = (blockIdx.x & 7) * cpx + (blockIdx.x >> 3);
  const int rowBase = (swz / nbn) << 8;
  const int colBase = (swz % nbn) << 8;

  // staging source pointers: thread t covers slots {h*1024 + L*512 + t};
  // logical (row = slot>>3, c = (slot&7) ^ (row&7)); LDS dest stays linear.
  const signed char* sA[2][2];
  const signed char* sB[2][2];
#pragma unroll
  for (int h = 0; h < 2; ++h)
#pragma unroll
    for (int L = 0; L < 2; ++L) {
      const int slot = h * 1024 + L * 512 + tid;
      const int row  = slot >> 3;
      const int c    = (slot & 7) ^ (row & 7);
      sA[h][L] = qx + (size_t)(rowBase + row) * K + c * 16;
      sB[h][L] = qw + (size_t)(colBase + row) * K + c * 16;
    }

  signed char* A0 = lds[0];
  signed char* B0 = lds[1];
  signed char* A1 = lds[2];
  signed char* B1 = lds[3];

#define STAGE(dst, src, h, kt)                                             \
  do {                                                                     \
    gload_lds16(src[h][0] + (kt) * BKB, (dst) + (h)*16384 + tid * 16);     \
    gload_lds16(src[h][1] + (kt) * BKB, (dst) + (h)*16384 + 8192 + tid * 16); \
  } while (0)

  // fragment-read addressing (row&7 == l15&7 since frag bases are mult of 16)
  const int ck0 = ((l4) ^ (l15 & 7)) * 16;       // ks=0 chunk offset
  const int ck1 = ((4 + l4) ^ (l15 & 7)) * 16;   // ks=1
  const int aRow0 = (wm * 128 + l15) * 128;
  const int bRow0 = (wn * 64 + l15) * 128;

  i32x4 acc[8][4] = {{{0}}};
  i32x4 af[4][2];
  i32x4 bf[4][2];

#define RDA(R, mb)                                                          \
  {                                                                         \
    _Pragma("unroll") for (int mi = 0; mi < 4; ++mi) {                      \
      af[mi][0] = *(const i32x4*)((R) + aRow0 + ((mb) + mi) * 2048 + ck0);  \
      af[mi][1] = *(const i32x4*)((R) + aRow0 + ((mb) + mi) * 2048 + ck1);  \
    }                                                                       \
  }
#define RDB(R, nb)                                                          \
  {                                                                         \
    _Pragma("unroll") for (int nj = 0; nj < 2; ++nj) {                      \
      bf[(nb) + nj][0] = *(const i32x4*)((R) + bRow0 + ((nb) + nj) * 2048 + ck0); \
      bf[(nb) + nj][1] = *(const i32x4*)((R) + bRow0 + ((nb) + nj) * 2048 + ck1); \
    }                                                                       \
  }
#define MFMAQ(mb, nb)                                                       \
  {                                                                         \
    _Pragma("unroll") for (int mi = 0; mi < 4; ++mi)                        \
        _Pragma("unroll") for (int nj = 0; nj < 2; ++nj)                    \
            _Pragma("unroll") for (int ks = 0; ks < 2; ++ks)                \
                acc[(mb) + mi][(nb) + nj] = __builtin_amdgcn_mfma_i32_16x16x64_i8( \
                    af[mi][ks], bf[(nb) + nj][ks], acc[(mb) + mi][(nb) + nj], 0, 0, 0); \
  }

  const int T = K / BKB;  // 32 K-tiles

  // prologue: tile0 -> A0/B0 (8 loads), tile1's B -> B1 (4 loads).
  // Gate tile0: every wave drains to <=4 outstanding (A0,B0 done; B1 may
  // float), THEN barrier -> all waves' A0/B0 loads are in LDS.
  STAGE(B0, sB, 0, 0); STAGE(B0, sB, 1, 0);
  STAGE(A0, sA, 0, 0); STAGE(A0, sA, 1, 0);
  STAGE(B1, sB, 0, 1); STAGE(B1, sB, 1, 1);
  VMCNT4();
  BARRIER();

  for (int it = 0; it < T / 2; ++it) {
    const int k1 = 2 * it + 1;
    const int k2 = (2 * it + 2 < T) ? 2 * it + 2 : T - 1;  // clamped (stale, never read)
    const int k3 = (2 * it + 3 < T) ? 2 * it + 3 : T - 1;

    // P1: read A0[M0]+B0[N0] (gated at prev end-P8 / prologue); stage A1h0 <- t+1
    RDA(A0, 0); RDB(B0, 0);
    STAGE(A1, sA, 0, k1);
    BARRIER(); LGKM0();
    __builtin_amdgcn_s_setprio(1); MFMAQ(0, 0); __builtin_amdgcn_s_setprio(0);
    BARRIER();

    // P2: read B0[N1]; stage A1h1 <- t+1
    RDB(B0, 2);
    STAGE(A1, sA, 1, k1);
    BARRIER(); LGKM0();
    __builtin_amdgcn_s_setprio(1); MFMAQ(0, 2); __builtin_amdgcn_s_setprio(0);
    BARRIER();

    // P3: read A0[M1]; stage B0h0 <- t+2 (B0 reads all done by P2's trailing barrier)
    RDA(A0, 4);
    STAGE(B0, sB, 0, k2);
    BARRIER(); LGKM0();
    __builtin_amdgcn_s_setprio(1); MFMAQ(4, 0); __builtin_amdgcn_s_setprio(0);
    BARRIER();

    // P4: stage B0h1 <- t+2. GATE tile t+1 (A1 from P1/P2, B1 from prev P7/P8):
    // vmcnt(4) leaves only P3/P4's B0 loads in flight; barrier publishes.
    STAGE(B0, sB, 1, k2);
    BARRIER(); LGKM0();
    __builtin_amdgcn_s_setprio(1); MFMAQ(4, 2); __builtin_amdgcn_s_setprio(0);
    VMCNT4();
    BARRIER();

    // P5: read A1[M0]+B1[N0] (gated at end-P4); stage A0h0 <- t+2
    RDA(A1, 0); RDB(B1, 0);
    STAGE(A0, sA, 0, k2);
    BARRIER(); LGKM0();
    __builtin_amdgcn_s_setprio(1); MFMAQ(0, 0); __builtin_amdgcn_s_setprio(0);
    BARRIER();

    // P6: read B1[N1]; stage A0h1 <- t+2
    RDB(B1, 2);
    STAGE(A0, sA, 1, k2);
    BARRIER(); LGKM0();
    __builtin_amdgcn_s_setprio(1); MFMAQ(0, 2); __builtin_amdgcn_s_setprio(0);
    BARRIER();

    // P7: read A1[M1]; stage B1h0 <- t+3
    RDA(A1, 4);
    STAGE(B1, sB, 0, k3);
    BARRIER(); LGKM0();
    __builtin_amdgcn_s_setprio(1); MFMAQ(4, 0); __builtin_amdgcn_s_setprio(0);
    BARRIER();

    // P8: stage B1h1 <- t+3. GATE tile t+2's A0/B0 (P3-P6 loads):
    // vmcnt(4) leaves only P7/P8's B1 loads in flight; barrier publishes.
    STAGE(B1, sB, 1, k3);
    BARRIER(); LGKM0();
    __builtin_amdgcn_s_setprio(1); MFMAQ(4, 2); __builtin_amdgcn_s_setprio(0);
    VMCNT4();
    BARRIER();
  }

  // epilogue: dequant + bias. C/D: col = lane&15, row = (lane>>4)*4 + reg
  const float dq = amax_x[0] * amax_w[0] * (1.0f / (127.0f * 127.0f));
#pragma unroll
  for (int nj = 0; nj < 4; ++nj) {
    const int col = colBase + wn * 64 + nj * 16 + l15;
    const float bv = bias[col];
#pragma unroll
    for (int mi = 0; mi < 8; ++mi) {
      const int row = rowBase + wm * 128 + mi * 16 + l4 * 4;
#pragma unroll
      for (int r = 0; r < 4; ++r)
        out[(size_t)(row + r) * M + col] = (float)acc[mi][nj][r] * dq + bv;
    }
  }
#undef STAGE
#undef RDA
#undef RDB
#undef MFMAQ
}

// ---------------------------------------------------------------------------
// Launch
// ---------------------------------------------------------------------------
extern "C" void kernel_launch(void* const* d_in, const int* in_sizes, int n_in,
                              void* d_out, int out_size, void* d_ws, size_t ws_size,
                              hipStream_t stream) {
  const float* x      = (const float*)d_in[0];
  const float* w      = (const float*)d_in[1];
  const float* bias   = (const float*)d_in[2];
  const float* amax_x = (const float*)d_in[3];
  const float* amax_w = (const float*)d_in[4];
  float* out = (float*)d_out;

  const int M = in_sizes[2];                    // 4096
  const int K = in_sizes[1] / M;                // 4096
  const int N = (int)((long)in_sizes[0] / K);   // 8192

  signed char* qx = (signed char*)d_ws;         // [N,K] int8
  signed char* qw = qx + (size_t)N * K;         // [M,K] int8

  const int nx4 = N * (K / 4);
  const int nw4 = M * (K / 4);
  quant_both_kernel<<<2048, 256, 0, stream>>>(x, w, qx, qw, amax_x, amax_w,
                                              nx4, nw4);

  const int nwg = (N / 256) * (M / 256);        // 512
  gemm_i8_8p<<<nwg, 512, 0, stream>>>(qx, qw, bias, amax_x, amax_w, out,
                                      N, M, K);
}